// Round 1
// baseline (901.529 us; speedup 1.0000x reference)
//
#include <hip/hip_runtime.h>

#define N_NODES 100000
#define N_EDGES 1600000
#define D 32

// ---------------------------------------------------------------------------
// Scatter-add: agg[receiver[e]] += edge_attr[e]  (one float4 per thread,
// 4 dword atomics). edge_attr reads fully coalesced.
// ---------------------------------------------------------------------------
__global__ __launch_bounds__(256) void scatter_kernel(
    const float4* __restrict__ edge_attr4,   // [N_EDGES * 8] float4
    const int* __restrict__ receivers,       // [N_EDGES]
    float* __restrict__ agg)                 // [N_NODES * 32]
{
    int idx = blockIdx.x * 256 + threadIdx.x;          // over N_EDGES*8 quads
    if (idx >= N_EDGES * 8) return;
    int edge = idx >> 3;
    int quad = idx & 7;
    float4 v = edge_attr4[idx];
    int r = receivers[edge];
    float* dst = agg + (size_t)r * D + quad * 4;
    atomicAdd(dst + 0, v.x);
    atomicAdd(dst + 1, v.y);
    atomicAdd(dst + 2, v.z);
    atomicAdd(dst + 3, v.w);
}

// ---------------------------------------------------------------------------
// Fused node MLP: out = relu([node, agg, g] @ W1 + b1) @ W2 + b2
// Globals part of layer 1 folded into per-block base vector (node-invariant).
// One node per thread; W1/W2 staged in LDS, read as broadcast float4.
// ---------------------------------------------------------------------------
__global__ __launch_bounds__(256) void mlp_kernel(
    const float* __restrict__ node_attr,
    const float* __restrict__ agg,
    const float* __restrict__ gattr,
    const float* __restrict__ W1,
    const float* __restrict__ b1,
    const float* __restrict__ W2,
    const float* __restrict__ b2,
    float* __restrict__ out)
{
    __shared__ float sW1n[1024];   // W1 rows 0..31  (node part)
    __shared__ float sW1a[1024];   // W1 rows 32..63 (agg part)
    __shared__ float sW2[1024];
    __shared__ float sBase[32];    // b1 + g @ W1[64:96, :]
    __shared__ float sB2[32];

    const int tid = threadIdx.x;
    for (int i = tid; i < 1024; i += 256) {
        sW1n[i] = W1[i];
        sW1a[i] = W1[1024 + i];
        sW2[i]  = W2[i];
    }
    if (tid < 32) {
        float acc = b1[tid];
        for (int k = 0; k < 32; ++k) acc += gattr[k] * W1[(64 + k) * 32 + tid];
        sBase[tid] = acc;
        sB2[tid] = b2[tid];
    }
    __syncthreads();

    const int node = blockIdx.x * 256 + tid;
    if (node >= N_NODES) return;

    float x[32], h[32];

    const float4* np4 = (const float4*)(node_attr + (size_t)node * D);
    #pragma unroll
    for (int q = 0; q < 8; ++q) {
        float4 v = np4[q];
        x[4*q+0] = v.x; x[4*q+1] = v.y; x[4*q+2] = v.z; x[4*q+3] = v.w;
    }
    #pragma unroll
    for (int j = 0; j < 32; ++j) h[j] = sBase[j];

    #pragma unroll 4
    for (int k = 0; k < 32; ++k) {
        float xk = x[k];
        #pragma unroll
        for (int q = 0; q < 8; ++q) {
            float4 w = *(const float4*)&sW1n[k * 32 + 4 * q];
            h[4*q+0] += xk * w.x; h[4*q+1] += xk * w.y;
            h[4*q+2] += xk * w.z; h[4*q+3] += xk * w.w;
        }
    }

    const float4* ap4 = (const float4*)(agg + (size_t)node * D);
    #pragma unroll
    for (int q = 0; q < 8; ++q) {
        float4 v = ap4[q];
        x[4*q+0] = v.x; x[4*q+1] = v.y; x[4*q+2] = v.z; x[4*q+3] = v.w;
    }
    #pragma unroll 4
    for (int k = 0; k < 32; ++k) {
        float xk = x[k];
        #pragma unroll
        for (int q = 0; q < 8; ++q) {
            float4 w = *(const float4*)&sW1a[k * 32 + 4 * q];
            h[4*q+0] += xk * w.x; h[4*q+1] += xk * w.y;
            h[4*q+2] += xk * w.z; h[4*q+3] += xk * w.w;
        }
    }

    #pragma unroll
    for (int j = 0; j < 32; ++j) h[j] = fmaxf(h[j], 0.0f);

    float o[32];
    #pragma unroll
    for (int j = 0; j < 32; ++j) o[j] = sB2[j];
    #pragma unroll 4
    for (int k = 0; k < 32; ++k) {
        float hk = h[k];
        #pragma unroll
        for (int q = 0; q < 8; ++q) {
            float4 w = *(const float4*)&sW2[k * 32 + 4 * q];
            o[4*q+0] += hk * w.x; o[4*q+1] += hk * w.y;
            o[4*q+2] += hk * w.z; o[4*q+3] += hk * w.w;
        }
    }

    float4* op4 = (float4*)(out + (size_t)node * D);
    #pragma unroll
    for (int q = 0; q < 8; ++q)
        op4[q] = make_float4(o[4*q+0], o[4*q+1], o[4*q+2], o[4*q+3]);
}

extern "C" void kernel_launch(void* const* d_in, const int* in_sizes, int n_in,
                              void* d_out, int out_size, void* d_ws, size_t ws_size,
                              hipStream_t stream) {
    const float* node_attr  = (const float*)d_in[0];
    const int*   edge_index = (const int*)d_in[1];
    const float* edge_attr  = (const float*)d_in[2];
    const float* gattr      = (const float*)d_in[3];
    const float* W1         = (const float*)d_in[4];
    const float* b1         = (const float*)d_in[5];
    const float* W2         = (const float*)d_in[6];
    const float* b2         = (const float*)d_in[7];
    float* out = (float*)d_out;

    const int* receivers = edge_index + N_EDGES;  // row 1 of [2, N_EDGES]

    float* agg = (float*)d_ws;                    // [N_NODES * 32] floats
    size_t agg_bytes = (size_t)N_NODES * D * sizeof(float);

    hipMemsetAsync(agg, 0, agg_bytes, stream);

    int scatter_threads = N_EDGES * 8;            // one float4 per thread
    scatter_kernel<<<(scatter_threads + 255) / 256, 256, 0, stream>>>(
        (const float4*)edge_attr, receivers, agg);

    mlp_kernel<<<(N_NODES + 255) / 256, 256, 0, stream>>>(
        node_attr, agg, gattr, W1, b1, W2, b2, out);
}

// Round 2
// 548.732 us; speedup vs baseline: 1.6429x; 1.6429x over previous
//
#include <hip/hip_runtime.h>

#define N_NODES 100000
#define N_EDGES 1600000
#define D 32

// ---------------------------------------------------------------------------
// Counting-sort pipeline: hist -> scan (3 small kernels) -> placement.
// Then one fused kernel: gather-reduce edges per node + 2-layer MLP.
// Workspace layout (ints): counts[100000] | offsets[100000] | cursor[100000]
//                          | blocksums[64] | sorted[1600000]   (~7.6 MB)
// ---------------------------------------------------------------------------

__global__ __launch_bounds__(256) void hist_kernel(
    const int* __restrict__ receivers, int* __restrict__ counts)
{
    int e = blockIdx.x * 256 + threadIdx.x;
    if (e >= N_EDGES) return;
    atomicAdd(&counts[receivers[e]], 1);
}

// Block-level exclusive scan: 49 blocks x 2048 elements (256 thr x 8 each).
__global__ __launch_bounds__(256) void scan_block_kernel(
    const int* __restrict__ counts, int* __restrict__ offsets,
    int* __restrict__ blocksums)
{
    __shared__ int lds[256];
    const int tid = threadIdx.x;
    const int base = blockIdx.x * 2048;

    int local[8];
    int s = 0;
    #pragma unroll
    for (int i = 0; i < 8; ++i) {
        int g = base + tid * 8 + i;
        int v = (g < N_NODES) ? counts[g] : 0;
        local[i] = s;          // exclusive prefix within this thread's chunk
        s += v;
    }
    lds[tid] = s;
    __syncthreads();
    // Hillis-Steele inclusive scan over 256 thread-totals
    for (int off = 1; off < 256; off <<= 1) {
        int v = lds[tid];
        int add = (tid >= off) ? lds[tid - off] : 0;
        __syncthreads();
        lds[tid] = v + add;
        __syncthreads();
    }
    int thread_excl = lds[tid] - s;
    #pragma unroll
    for (int i = 0; i < 8; ++i) {
        int g = base + tid * 8 + i;
        if (g < N_NODES) offsets[g] = thread_excl + local[i];
    }
    if (tid == 255) blocksums[blockIdx.x] = lds[255];
}

// Single wave scans the 49 block totals (exclusive, in place).
__global__ __launch_bounds__(64) void scan_sums_kernel(
    int* __restrict__ blocksums, int nb)
{
    int tid = threadIdx.x;
    int v = (tid < nb) ? blocksums[tid] : 0;
    int orig = v;
    #pragma unroll
    for (int off = 1; off < 64; off <<= 1) {
        int n = __shfl_up(v, off, 64);
        if (tid >= off) v += n;
    }
    if (tid < nb) blocksums[tid] = v - orig;
}

__global__ __launch_bounds__(256) void add_base_kernel(
    int* __restrict__ offsets, const int* __restrict__ blocksums,
    int* __restrict__ cursor)
{
    int idx = blockIdx.x * 256 + threadIdx.x;
    if (idx >= N_NODES) return;
    int v = offsets[idx] + blocksums[idx >> 11];
    offsets[idx] = v;
    cursor[idx] = v;
}

__global__ __launch_bounds__(256) void placement_kernel(
    const int* __restrict__ receivers, int* __restrict__ cursor,
    int* __restrict__ sorted)
{
    int e = blockIdx.x * 256 + threadIdx.x;
    if (e >= N_EDGES) return;
    int p = atomicAdd(&cursor[receivers[e]], 1);
    sorted[p] = e;
}

// ---------------------------------------------------------------------------
// Fused: agg[n] = sum of edge rows (via CSR gather), then
// out = relu([node, agg, g] @ W1 + b1) @ W2 + b2.  One node per thread.
// Globals part of layer 1 folded into per-block base vector.
// ---------------------------------------------------------------------------
__global__ __launch_bounds__(256) void node_kernel(
    const float* __restrict__ node_attr,
    const float* __restrict__ edge_attr,
    const int* __restrict__ sorted,
    const int* __restrict__ offsets,
    const int* __restrict__ counts,
    const float* __restrict__ gattr,
    const float* __restrict__ W1,
    const float* __restrict__ b1,
    const float* __restrict__ W2,
    const float* __restrict__ b2,
    float* __restrict__ out)
{
    __shared__ float sW1n[1024];   // W1 rows 0..31  (node part)
    __shared__ float sW1a[1024];   // W1 rows 32..63 (agg part)
    __shared__ float sW2[1024];
    __shared__ float sBase[32];    // b1 + g @ W1[64:96, :]
    __shared__ float sB2[32];

    const int tid = threadIdx.x;
    for (int i = tid; i < 1024; i += 256) {
        sW1n[i] = W1[i];
        sW1a[i] = W1[1024 + i];
        sW2[i]  = W2[i];
    }
    if (tid < 32) {
        float acc = b1[tid];
        for (int k = 0; k < 32; ++k) acc += gattr[k] * W1[(64 + k) * 32 + tid];
        sBase[tid] = acc;
        sB2[tid] = b2[tid];
    }
    __syncthreads();

    const int node = blockIdx.x * 256 + tid;
    if (node >= N_NODES) return;

    // ---- gather-reduce incoming edges ----
    float acc[32];
    #pragma unroll
    for (int j = 0; j < 32; ++j) acc[j] = 0.0f;

    const int off = offsets[node];
    const int cnt = counts[node];
    for (int i = 0; i < cnt; ++i) {
        int e = sorted[off + i];
        const float4* r4 = (const float4*)(edge_attr + (size_t)e * D);
        #pragma unroll
        for (int q = 0; q < 8; ++q) {
            float4 v = r4[q];
            acc[4*q+0] += v.x; acc[4*q+1] += v.y;
            acc[4*q+2] += v.z; acc[4*q+3] += v.w;
        }
    }

    // ---- layer 1 ----
    float h[32];
    #pragma unroll
    for (int j = 0; j < 32; ++j) h[j] = sBase[j];

    const float4* np4 = (const float4*)(node_attr + (size_t)node * D);
    #pragma unroll
    for (int q0 = 0; q0 < 8; ++q0) {
        float4 xv = np4[q0];
        float xk[4] = {xv.x, xv.y, xv.z, xv.w};
        #pragma unroll
        for (int kk = 0; kk < 4; ++kk) {
            int k = 4 * q0 + kk;
            #pragma unroll
            for (int q = 0; q < 8; ++q) {
                float4 w = *(const float4*)&sW1n[k * 32 + 4 * q];
                h[4*q+0] += xk[kk] * w.x; h[4*q+1] += xk[kk] * w.y;
                h[4*q+2] += xk[kk] * w.z; h[4*q+3] += xk[kk] * w.w;
            }
        }
    }
    #pragma unroll 4
    for (int k = 0; k < 32; ++k) {
        float ak = acc[k];
        #pragma unroll
        for (int q = 0; q < 8; ++q) {
            float4 w = *(const float4*)&sW1a[k * 32 + 4 * q];
            h[4*q+0] += ak * w.x; h[4*q+1] += ak * w.y;
            h[4*q+2] += ak * w.z; h[4*q+3] += ak * w.w;
        }
    }
    #pragma unroll
    for (int j = 0; j < 32; ++j) h[j] = fmaxf(h[j], 0.0f);

    // ---- layer 2 ----
    float o[32];
    #pragma unroll
    for (int j = 0; j < 32; ++j) o[j] = sB2[j];
    #pragma unroll 4
    for (int k = 0; k < 32; ++k) {
        float hk = h[k];
        #pragma unroll
        for (int q = 0; q < 8; ++q) {
            float4 w = *(const float4*)&sW2[k * 32 + 4 * q];
            o[4*q+0] += hk * w.x; o[4*q+1] += hk * w.y;
            o[4*q+2] += hk * w.z; o[4*q+3] += hk * w.w;
        }
    }

    float4* op4 = (float4*)(out + (size_t)node * D);
    #pragma unroll
    for (int q = 0; q < 8; ++q)
        op4[q] = make_float4(o[4*q+0], o[4*q+1], o[4*q+2], o[4*q+3]);
}

extern "C" void kernel_launch(void* const* d_in, const int* in_sizes, int n_in,
                              void* d_out, int out_size, void* d_ws, size_t ws_size,
                              hipStream_t stream) {
    const float* node_attr  = (const float*)d_in[0];
    const int*   edge_index = (const int*)d_in[1];
    const float* edge_attr  = (const float*)d_in[2];
    const float* gattr      = (const float*)d_in[3];
    const float* W1         = (const float*)d_in[4];
    const float* b1         = (const float*)d_in[5];
    const float* W2         = (const float*)d_in[6];
    const float* b2         = (const float*)d_in[7];
    float* out = (float*)d_out;

    const int* receivers = edge_index + N_EDGES;   // row 1 of [2, N_EDGES]

    // workspace layout
    int* counts    = (int*)d_ws;                   // [N_NODES]
    int* offsets   = counts + N_NODES;             // [N_NODES]
    int* cursor    = offsets + N_NODES;            // [N_NODES]
    int* blocksums = cursor + N_NODES;             // [64]
    int* sorted    = blocksums + 64;               // [N_EDGES]

    const int SCAN_BLOCKS = (N_NODES + 2047) / 2048;   // 49

    hipMemsetAsync(counts, 0, N_NODES * sizeof(int), stream);

    hist_kernel<<<(N_EDGES + 255) / 256, 256, 0, stream>>>(receivers, counts);

    scan_block_kernel<<<SCAN_BLOCKS, 256, 0, stream>>>(counts, offsets, blocksums);
    scan_sums_kernel<<<1, 64, 0, stream>>>(blocksums, SCAN_BLOCKS);
    add_base_kernel<<<(N_NODES + 255) / 256, 256, 0, stream>>>(offsets, blocksums, cursor);

    placement_kernel<<<(N_EDGES + 255) / 256, 256, 0, stream>>>(receivers, cursor, sorted);

    node_kernel<<<(N_NODES + 255) / 256, 256, 0, stream>>>(
        node_attr, edge_attr, sorted, offsets, counts,
        gattr, W1, b1, W2, b2, out);
}